// Round 9
// baseline (322.698 us; speedup 1.0000x reference)
//
#include <hip/hip_runtime.h>
#include <math.h>

constexpr int N_NODES = 100000;
constexpr int N_EDGES = 1600000;
constexpr int F_IN    = 128;
constexpr int F_H     = 64;
constexpr float NEG_SLOPE = 0.2f;

constexpr int NBUCK  = (N_NODES + 255) / 256;  // 391 buckets of 256 dst nodes
constexpr int BUFCAP = 6144;                   // per-bucket stream cap (mean 4092, +32 sigma)
constexpr int LCAP   = 6144;
constexpr int CPAD   = 16;                     // gcur stride: one 64B line per counter

// staged multisplit params
constexpr int SB   = 64;
constexpr int EPT  = 4;
constexpr int EPR  = 256 * EPT;
constexpr int G    = 16;
constexpr int BCAP = 48;

__device__ inline float lrelu(float v) { return v > 0.f ? v : NEG_SLOPE * v; }
__device__ inline unsigned short f2b(float f) {          // fp32 -> bf16 RNE
    unsigned x = __float_as_uint(f);
    return (unsigned short)((x + 0x7fffu + ((x >> 16) & 1u)) >> 16);
}
__device__ inline float b2f(unsigned short u) { return __uint_as_float(((unsigned)u) << 16); }

// ---------------- GEMM: lane = row, W via wave-uniform scalar loads; h1 stored bf16 ----------------
__global__ __launch_bounds__(64) void k_gemm1(
    const float* __restrict__ x, const float* __restrict__ W1,
    const float* __restrict__ a_s, const float* __restrict__ a_d,
    unsigned short* __restrict__ h1b, float* __restrict__ as1, float* __restrict__ ad1)
{
    const int row = blockIdx.x * 64 + threadIdx.x;
    if (row >= N_NODES) return;

    float acc[F_H];
#pragma unroll
    for (int f = 0; f < F_H; ++f) acc[f] = 0.f;

    const float4* __restrict__ xr = (const float4*)(x + (size_t)row * F_IN);
    for (int k4 = 0; k4 < F_IN / 4; ++k4) {
        const float4 xv = xr[k4];
        const float* __restrict__ wk = W1 + (size_t)k4 * 4 * F_H;
#pragma unroll
        for (int kk = 0; kk < 4; ++kk) {
            const float xs = (kk == 0) ? xv.x : (kk == 1) ? xv.y : (kk == 2) ? xv.z : xv.w;
            const float* __restrict__ w = wk + kk * F_H;   // wave-uniform -> scalar loads
#pragma unroll
            for (int f = 0; f < F_H; ++f)
                acc[f] = fmaf(xs, w[f], acc[f]);
        }
    }

    float vs = 0.f, vd = 0.f;
#pragma unroll
    for (int f = 0; f < F_H; ++f) {
        vs = fmaf(acc[f], a_s[f], vs);
        vd = fmaf(acc[f], a_d[f], vd);
    }
    as1[row] = vs;
    ad1[row] = vd;

    unsigned up[F_H / 2];
#pragma unroll
    for (int q = 0; q < F_H / 2; ++q)
        up[q] = (unsigned)f2b(acc[2 * q]) | ((unsigned)f2b(acc[2 * q + 1]) << 16);
    uint4* __restrict__ hr = (uint4*)(h1b + (size_t)row * F_H);
#pragma unroll
    for (int q = 0; q < F_H / 8; ++q)
        hr[q] = make_uint4(up[4 * q], up[4 * q + 1], up[4 * q + 2], up[4 * q + 3]);
}

// ---------------- Staged multisplit bucketize: LDS bins, aligned 16-dword flushes ----------------
__global__ __launch_bounds__(256) void k_bucketize_staged(
    const int* __restrict__ ei, int* __restrict__ gcur, unsigned* __restrict__ buf)
{
    __shared__ unsigned bin_buf[NBUCK][BCAP];   // ~75 KB
    __shared__ int bin_cnt[NBUCK];

    const int t = threadIdx.x;
    for (int i = t; i < NBUCK; i += 256) bin_cnt[i] = 0;
    __syncthreads();

    const int per = N_EDGES / SB;               // 25000
    const int e0 = blockIdx.x * per;
    const int e1 = (blockIdx.x == SB - 1) ? N_EDGES : (e0 + per);

    int cs[EPT], cd[EPT];
#pragma unroll
    for (int q = 0; q < EPT; ++q) {
        const int i = e0 + q * 256 + t;
        cs[q] = (i < e1) ? ei[i] : -1;
        cd[q] = (i < e1) ? ei[N_EDGES + i] : 0;
    }

    for (int base = e0; base < e1; base += EPR) {
        int ls[EPT], ld[EPT];
#pragma unroll
        for (int q = 0; q < EPT; ++q) { ls[q] = cs[q]; ld[q] = cd[q]; }
        const int nbase = base + EPR;
        if (nbase < e1) {
#pragma unroll
            for (int q = 0; q < EPT; ++q) {
                const int i = nbase + q * 256 + t;
                cs[q] = (i < e1) ? ei[i] : -1;
                cd[q] = (i < e1) ? ei[N_EDGES + i] : 0;
            }
        }
#pragma unroll
        for (int q = 0; q < EPT; ++q) {
            if (ls[q] >= 0) {
                const int b = ld[q] >> 8;
                const int pos = atomicAdd(&bin_cnt[b], 1);
                if (pos < BCAP)
                    bin_buf[b][pos] = ((unsigned)ls[q] << 8) | (unsigned)(ld[q] & 255);
            }
        }
        __syncthreads();
        for (int bb = t; bb < NBUCK; bb += 256) {
            const int cnt = bin_cnt[bb];
            if (cnt >= G) {
                const int take = cnt & ~(G - 1);
                const int gbase = atomicAdd(&gcur[bb * CPAD], take);
                if (gbase + take <= BUFCAP) {
                    unsigned* __restrict__ dst = buf + (size_t)bb * BUFCAP + gbase;
                    const int src0 = cnt - take;
                    for (int u = 0; u < take; u += 4) {
                        uint4 v;
                        v.x = bin_buf[bb][src0 + u];
                        v.y = bin_buf[bb][src0 + u + 1];
                        v.z = bin_buf[bb][src0 + u + 2];
                        v.w = bin_buf[bb][src0 + u + 3];
                        *(uint4*)(dst + u) = v;
                    }
                }
                bin_cnt[bb] = cnt - take;
            }
        }
        __syncthreads();
    }
    for (int bb = t; bb < NBUCK; bb += 256) {
        const int cnt = bin_cnt[bb];
        if (cnt > 0) {
            const int gbase = atomicAdd(&gcur[bb * CPAD], cnt);
            if (gbase + cnt <= BUFCAP) {
                unsigned* __restrict__ dst = buf + (size_t)bb * BUFCAP + gbase;
                for (int u = 0; u < cnt; ++u) dst[u] = bin_buf[bb][u];
            }
        }
    }
}

// ---------------- Bucket-total scan ----------------
__global__ __launch_bounds__(512) void k_bscan(const int* __restrict__ gcur, int* __restrict__ boff)
{
    __shared__ int sm[512];
    const int t = threadIdx.x;
    const int m = (t < NBUCK) ? min(gcur[t * CPAD], BUFCAP) : 0;
    sm[t] = m;
    __syncthreads();
    for (int o = 1; o < 512; o <<= 1) {
        int a = (t >= o) ? sm[t - o] : 0;
        __syncthreads();
        sm[t] += a;
        __syncthreads();
    }
    if (t < NBUCK) boff[t] = sm[t] - m;   // exclusive
}

// ---------------- Per-bucket CSR build in LDS, dense global write ----------------
__global__ __launch_bounds__(1024) void k_csr_build(
    const int* __restrict__ gcur, const unsigned* __restrict__ buf, const int* __restrict__ boff,
    int* __restrict__ row_start, int* __restrict__ csr)
{
    __shared__ int lcsr[LCAP];      // 24 KB
    __shared__ int hist[256];
    __shared__ int lstart[257];
    __shared__ int lcur[256];

    const int b  = blockIdx.x;
    const int t  = threadIdx.x;
    const int nd = min(256, N_NODES - (b << 8));
    const int m  = min(gcur[b * CPAD], BUFCAP);
    const unsigned* __restrict__ sb = buf + (size_t)b * BUFCAP;

    if (t < 256) hist[t] = 0;
    __syncthreads();

    for (int i = t; i < m; i += 1024) atomicAdd(&hist[sb[i] & 255], 1);
    __syncthreads();

    for (int o = 1; o < 256; o <<= 1) {
        int a = 0;
        if (t < 256 && t >= o) a = hist[t - o];
        __syncthreads();
        if (t < 256) hist[t] += a;
        __syncthreads();
    }
    if (t < 256) { lstart[t + 1] = hist[t]; lcur[t] = 0; }
    if (t == 0) lstart[0] = 0;
    __syncthreads();

    for (int i = t; i < m; i += 1024) {
        const unsigned v = sb[i];
        const int dl = v & 255;
        const int p  = atomicAdd(&lcur[dl], 1);
        const int pp = lstart[dl] + p;
        if (pp < LCAP) lcsr[pp] = (int)(v >> 8);
    }
    __syncthreads();

    const int gb   = boff[b];
    const int mtot = lstart[256];
    for (int i = t; i < mtot; i += 1024) csr[gb + i] = lcsr[i];
    if (t < nd) row_start[(b << 8) + t + 1] = gb + lstart[t + 1];
    if (b == 0 && t == 0) row_start[0] = 0;
}

// ---------------- Layer-1 aggregate: wave per dst, bf16 gather, LDS (s,p) broadcast ----------------
__global__ __launch_bounds__(256) void k_agg1(
    const int* __restrict__ row_start, const int* __restrict__ csr,
    const float* __restrict__ as1, const float* __restrict__ ad1,
    const unsigned short* __restrict__ h1b,
    const float* __restrict__ b1, const float* __restrict__ W2,
    const float* __restrict__ a_s2, const float* __restrict__ a_d2,
    float* __restrict__ h2, float* __restrict__ as2, float* __restrict__ ad2)
{
    __shared__ int2 pairs[4][64];   // per-wave (src, p) broadcast buffer, 2 KB

    const int wv = threadIdx.x >> 6;
    const int j  = threadIdx.x & 63;
    const int n  = blockIdx.x * 4 + wv;
    if (n >= N_NODES) return;

    const int r0  = row_start[n];
    const int deg = row_start[n + 1] - r0;   // real in-edges; +1 implicit self
    const float ad = ad1[n];
    const unsigned short* __restrict__ hj = h1b + j;

    float acc = 0.f, den_l = 0.f;

    if (deg <= 63) {               // fast path: edges + self in one wave chunk
        int   sj = n;              // lane 'deg' holds the self edge
        float aj = (j == deg) ? as1[n] : -INFINITY;
        if (j < deg) { sj = csr[r0 + j]; aj = as1[sj]; }
        float rm = aj;
#pragma unroll
        for (int o = 32; o; o >>= 1) rm = fmaxf(rm, __shfl_xor(rm, o, 64));
        const float mv = lrelu(rm + ad);
        float pj = 0.f;
        if (j <= deg) pj = __expf(lrelu(aj + ad) - mv);
        den_l = pj;

        pairs[wv][j] = make_int2(sj, __float_as_int(pj));
        const int tot = deg + 1;
        int u = 0;
        for (; u + 8 <= tot; u += 8) {
#pragma unroll
            for (int k = 0; k < 8; ++k) {
                const int2 q = pairs[wv][u + k];
                acc = fmaf(__int_as_float(q.y), b2f(hj[(size_t)q.x << 6]), acc);
            }
        }
        for (; u < tot; ++u) {
            const int2 q = pairs[wv][u];
            acc = fmaf(__int_as_float(q.y), b2f(hj[(size_t)q.x << 6]), acc);
        }
    } else {                       // generic chunked path + explicit self term
        float rml = (j == 0) ? as1[n] : -INFINITY;
        for (int idx = r0 + j; idx < r0 + deg; idx += 64) rml = fmaxf(rml, as1[csr[idx]]);
        float rm = rml;
#pragma unroll
        for (int o = 32; o; o >>= 1) rm = fmaxf(rm, __shfl_xor(rm, o, 64));
        const float mv = lrelu(rm + ad);

        {   // self edge
            const float ps = __expf(lrelu(as1[n] + ad) - mv);
            if (j == 0) den_l += ps;
            acc = fmaf(ps, b2f(hj[(size_t)n << 6]), acc);
        }
        for (int base = r0; base < r0 + deg; base += 64) {
            const int cnt = min(64, r0 + deg - base);
            int sj = 0; float pj = 0.f;
            if (j < cnt) { sj = csr[base + j]; pj = __expf(lrelu(as1[sj] + ad) - mv); }
            den_l += pj;
            pairs[wv][j] = make_int2(sj, __float_as_int(pj));
            int u = 0;
            for (; u + 8 <= cnt; u += 8) {
#pragma unroll
                for (int k = 0; k < 8; ++k) {
                    const int2 q = pairs[wv][u + k];
                    acc = fmaf(__int_as_float(q.y), b2f(hj[(size_t)q.x << 6]), acc);
                }
            }
            for (; u < cnt; ++u) {
                const int2 q = pairs[wv][u];
                acc = fmaf(__int_as_float(q.y), b2f(hj[(size_t)q.x << 6]), acc);
            }
        }
    }

    float den = den_l;
#pragma unroll
    for (int o = 32; o; o >>= 1) den += __shfl_xor(den, o, 64);

    // layer-1 epilogue + 64x2 layer-2 GEMM + alpha2
    float v = acc / (den + 1e-16f) + b1[j];
    v = v > 0.f ? v : 0.f;
    float c0 = v * W2[j * 2 + 0];
    float c1 = v * W2[j * 2 + 1];
#pragma unroll
    for (int o = 32; o; o >>= 1) {
        c0 += __shfl_xor(c0, o, 64);
        c1 += __shfl_xor(c1, o, 64);
    }
    if (j == 0) {
        h2[n * 2 + 0] = c0;
        h2[n * 2 + 1] = c1;
        as2[n] = c0 * a_s2[0] + c1 * a_s2[1];
        ad2[n] = c0 * a_d2[0] + c1 * a_d2[1];
    }
}

// ---------------- Layer-2 aggregate: 8 lanes per dst node (latency hiding) ----------------
__global__ __launch_bounds__(256) void k_agg2(
    const int* __restrict__ row_start, const int* __restrict__ csr,
    const float* __restrict__ as2, const float* __restrict__ ad2,
    const float* __restrict__ h2, const float* __restrict__ b2,
    float* __restrict__ out)
{
    const int t   = threadIdx.x;
    const int n   = blockIdx.x * 32 + (t >> 3);
    const int sub = t & 7;
    if (n >= N_NODES) return;
    const int r0 = row_start[n], r1 = row_start[n + 1];
    const float ad = ad2[n];
    const float2* __restrict__ h22 = (const float2*)h2;

    float rm = (sub == 0) ? as2[n] : -INFINITY;   // self edge on sub 0
    for (int idx = r0 + sub; idx < r1; idx += 8) rm = fmaxf(rm, as2[csr[idx]]);
#pragma unroll
    for (int o = 1; o < 8; o <<= 1) rm = fmaxf(rm, __shfl_xor(rm, o, 64));
    const float mv = lrelu(rm + ad);

    float den = 0.f, x0 = 0.f, x1 = 0.f;
    if (sub == 0) {
        const float p = __expf(lrelu(as2[n] + ad) - mv);
        const float2 g = h22[n];
        den = p; x0 = p * g.x; x1 = p * g.y;
    }
    for (int idx = r0 + sub; idx < r1; idx += 8) {
        const int s = csr[idx];
        const float p = __expf(lrelu(as2[s] + ad) - mv);
        const float2 g = h22[s];
        den += p;
        x0 = fmaf(p, g.x, x0);
        x1 = fmaf(p, g.y, x1);
    }
#pragma unroll
    for (int o = 1; o < 8; o <<= 1) {
        den += __shfl_xor(den, o, 64);
        x0  += __shfl_xor(x0,  o, 64);
        x1  += __shfl_xor(x1,  o, 64);
    }
    if (sub == 0) {
        const float inv = 1.f / (den + 1e-16f);
        out[n * 2 + 0] = x0 * inv + b2[0];
        out[n * 2 + 1] = x1 * inv + b2[1];
    }
}

extern "C" void kernel_launch(void* const* d_in, const int* in_sizes, int n_in,
                              void* d_out, int out_size, void* d_ws, size_t ws_size,
                              hipStream_t stream)
{
    const float* x    = (const float*)d_in[0];
    const int*   ei   = (const int*)d_in[1];
    const float* W1   = (const float*)d_in[2];
    const float* as1w = (const float*)d_in[3];
    const float* ad1w = (const float*)d_in[4];
    const float* b1   = (const float*)d_in[5];
    const float* W2   = (const float*)d_in[6];
    const float* as2w = (const float*)d_in[7];
    const float* ad2w = (const float*)d_in[8];
    const float* b2   = (const float*)d_in[9];
    float* out = (float*)d_out;

    float* ws = (float*)d_ws;
    size_t off = 0;
    unsigned short* h1b = (unsigned short*)(ws + off); off += (size_t)N_NODES * F_H / 2;  // 12.8 MB bf16
    float* as1 = ws + off; off += N_NODES;
    float* ad1 = ws + off; off += N_NODES;
    float* h2  = ws + off; off += (size_t)N_NODES * 2;
    float* as2 = ws + off; off += N_NODES;
    float* ad2 = ws + off; off += N_NODES;
    int* gcur      = (int*)(ws + off); off += NBUCK * CPAD;
    unsigned* buf  = (unsigned*)(ws + off); off += (size_t)NBUCK * BUFCAP;  // 9.6 MB
    int* boff      = (int*)(ws + off); off += NBUCK + 1;
    int* row_start = (int*)(ws + off); off += N_NODES + 1;
    int* csr       = (int*)(ws + off); off += N_EDGES;

    hipMemsetAsync(gcur, 0, NBUCK * CPAD * sizeof(int), stream);

    k_gemm1           <<<(N_NODES + 63) / 64, 64, 0, stream>>>(x, W1, as1w, ad1w, h1b, as1, ad1);
    k_bucketize_staged<<<SB, 256, 0, stream>>>(ei, gcur, buf);
    k_bscan           <<<1, 512, 0, stream>>>(gcur, boff);
    k_csr_build       <<<NBUCK, 1024, 0, stream>>>(gcur, buf, boff, row_start, csr);
    k_agg1            <<<(N_NODES + 3) / 4, 256, 0, stream>>>(
        row_start, csr, as1, ad1, h1b, b1, W2, as2w, ad2w, h2, as2, ad2);
    k_agg2            <<<(N_NODES + 31) / 32, 256, 0, stream>>>(row_start, csr, as2, ad2, h2, b2, out);
}